// Round 6
// baseline (179.790 us; speedup 1.0000x reference)
//
#include <hip/hip_runtime.h>
#include <math.h>
#include <stdint.h>

// ---------------- problem constants ----------------
#define KK     9     // corners
#define NCLS   13
#define NANC   5     // anchors
#define NBB    128
#define NHH    26
#define NWW    26
#define NTT    50    // targets
#define LL     21    // 2K+3
#define CHC    32    // 2K+1+NC channels per anchor
#define NPIX   676   // NH*NW
#define NANCHT 3380  // NA*NPIX
#define NCELLT 432640 // NB*NANCHT
#define GTS    20    // floats per target in packed gt layout
#define MWPB   106   // mask words per batch (ceil(3380/32) padded)
#define NBLKX  53    // ceil(NANCHT/64) cell-groups per batch
#define QMAX   3200  // 64 cells x 50 targets: exact worst case, no overflow cliff

// corner-bin grid: 19.2-px bins; exclusion needs an aligned-corner distance
// < 16.98 px, so a 3x3 (dilated) window of 19.2-px bins around the predicted
// corner's bin is a guaranteed superset. 640/19.2 -> 34 x-bins, 480/19.2 -> 25.
#define BINNX  34
#define BINNY  25
#define BININV (1.0f/19.2f)
#define BPB    (KK*BINNY)          // bitmap u64 words per batch (225)
#define MPB    (KK*BINNY*BINNX)    // mask u64 words per batch (7650)

// derived float constants (computed in double, rounded once)
#define LOG2E_F   1.4426950408889634f
#define K1C       2.8853900817779268f   // SHARP*log2e
#define K2C       0.036067376022224085f // K1C/TH
#define SXW       24.615384615384617f   // 640/26
#define SYH       18.461538461538463f   // 480/26
#define THRESH_S  43.500902934225507f   // 9 + SIL*9*(e^2-1)
#define CONF_T_SCALE 0.017390849194407297f // (1/(e^2-1))/9
#define OBJ_W     5.0f
#define EPOCH_PRETRAIN 15
#define BIGV      6.0e18f               // pad sentinel in gts_neg (exact path skips via layout)

typedef __attribute__((ext_vector_type(2))) float f2;

static __device__ __forceinline__ float fast_exp2(float x){
  return __builtin_amdgcn_exp2f(x);
}
static __device__ __forceinline__ float fast_sqrt(float x){
  return __builtin_amdgcn_sqrtf(x);
}
static __device__ __forceinline__ float sigmoidf_(float x){
  return 1.0f/(1.0f + fast_exp2(-LOG2E_F*x));
}

__constant__ float c_anch[10] = {1.482f,2.2412f,2.0501f,3.1265f,2.3946f,4.6891f,
                                 3.1018f,3.991f,3.4879f,5.8851f};

// ws layout (bytes):
//   [0,4096)          : bc_part  double[NBB][4]
//   [4096,58368)      : partials double[NBB*NBLKX]
//   [58368,570368)    : gts_neg  float[NBB*NTT*GTS]   NEGATED px corners (f32):
//                         per (b,t): [x0..x8, BIG, y0..y8, BIG]
//   [570368,570880)   : nvalid   int[NBB]
//   [570880,625152)   : maskw    u32[NBB*MWPB]        bit-packed conf_mask0
//   [625152,8458752)  : masksD   u64[NBB][KK][BINNY][BINNX] dilated per-bin target masks
//   [8458752,8689152) : bitmapD  u64[NBB][KK][BINNY]  dilated per-row occupancy bitmaps

// ---------------- phase 0: prep (nv; f32 gt table; corner-bin scatter) ----------------
__global__ __launch_bounds__(256) void prep_kernel(const float* __restrict__ tgt,
                                                   float* __restrict__ gts_neg,
                                                   unsigned long long* __restrict__ masksD,
                                                   unsigned long long* __restrict__ bitmapD,
                                                   int* __restrict__ nvalid){
  int b = blockIdx.x;
  int tid = threadIdx.x;
  const float* trow = tgt + (size_t)b*NTT*LL;
  __shared__ int snv;
  if (tid < 64){
    float v1 = (tid < NTT) ? trow[tid*LL + 1] : 0.0f;
    unsigned long long mk = __ballot(tid < NTT && v1 != 0.0f);
    int firstInvalid = __ffsll(~mk) - 1;        // prefix length (cumprod semantics)
    if (tid == 0){ snv = firstInvalid; nvalid[b] = firstInvalid; }
  }
  __syncthreads();
  int nv = snv;

  // f32 negated-corner table (drain path, reference-identical values)
  for (int idx = tid; idx < NTT*GTS; idx += 256){
    int tt = idx / GTS;
    int c  = idx - tt*GTS;
    float v;
    if (c == 9 || c == 19)      v = BIGV;
    else if (c < 9)             v = -(trow[tt*LL + 1 + 2*c] * 640.0f);
    else                        v = -(trow[tt*LL + 2 + 2*(c-10)] * 480.0f);
    gts_neg[(size_t)b*NTT*GTS + idx] = v;
  }

  // corner scatter into dilated bitmap + dilated target masks (zeroed by memset)
  unsigned long long* mb_ = masksD  + (size_t)b*MPB;
  unsigned long long* bb_ = bitmapD + (size_t)b*BPB;
  for (int idx = tid; idx < NTT*KK; idx += 256){
    int t = idx / KK, k = idx - t*KK;
    if (t >= nv) continue;
    float gx = trow[t*LL + 1 + 2*k] * 640.0f;
    float gy = trow[t*LL + 2 + 2*k] * 480.0f;
    int bx = (int)floorf(gx * BININV);
    int by = (int)floorf(gy * BININV);
    bx = min(max(bx, 0), BINNX-1);
    by = min(max(by, 0), BINNY-1);
    unsigned long long tb = 1ull << t;
    unsigned long long rowbits = (bx == 0) ? 3ull : (7ull << (bx-1));
    for (int dy = -1; dy <= 1; ++dy){
      int yy = by + dy;
      if (yy < 0 || yy > BINNY-1) continue;
      atomicOr(&bb_[k*BINNY + yy], rowbits);
      for (int dx = -1; dx <= 1; ++dx){
        int xx = bx + dx;
        if (xx < 0 || xx > BINNX-1) continue;
        atomicOr(&mb_[(k*BINNY + yy)*BINNX + xx], tb);
      }
    }
  }
}

// ---------------- phase A: bin-test candidate search + queued exact f32 path ----------------
// Block = 64 cells x 4 waves.
//  (1) waves cooperatively compute the 19 channel values for the 64 cells ONCE
//      into LDS (sPx/sPy f32 pixel-scale pairs, sCf sigmoid'd conf);
//  (2) per thread: 9 corners -> bin index -> LDS bitmap bit test -> on hit, OR
//      the global dilated target-mask into qbits  (~100 ops vs ~1250 pair-cull);
//  (3) wave-prefix push of qbits into an LDS queue; all 256 threads drain it
//      with reference-identical f32 math; exclusions OR into a bitmask.
__global__ __launch_bounds__(256) void region_confmask_kernel(
    const float* __restrict__ outp, const float* __restrict__ gts_neg,
    const unsigned long long* __restrict__ masksD,
    const unsigned long long* __restrict__ bitmapD,
    const int* __restrict__ nvalid, unsigned int* __restrict__ maskw,
    double* __restrict__ partials){
  int b    = blockIdx.y;
  int tid  = threadIdx.x;
  int lane = tid & 63;
  int w    = tid >> 6;                          // wave 0..3
  int cellbase = blockIdx.x * 64;
  int cell = cellbase + lane;
  bool live = (cell < NANCHT);
  int cellc = live ? cell : (NANCHT-1);

  __shared__ float sgt[NTT*GTS] __attribute__((aligned(16)));   // 4000 B f32 gt
  __shared__ unsigned long long sbm[BPB];                       // 1800 B bitmap
  __shared__ f2 sPx[5*64] __attribute__((aligned(8)));          // 2560 B P x-pairs
  __shared__ f2 sPy[5*64] __attribute__((aligned(8)));          // 2560 B P y-pairs
  __shared__ float sCf[64];                                     // sigmoid(conf)
  __shared__ unsigned short qlist[QMAX];                        // 6400 B queue
  __shared__ int qcount;
  __shared__ unsigned int sexclw[2];

  if (tid == 0) qcount = 0;
  if (tid < 2) sexclw[tid] = 0u;

  // stage gt table + bitmap
  {
    const float* fsrc = gts_neg + (size_t)b*NTT*GTS;
    for (int idx = tid; idx < NTT*GTS; idx += 256) sgt[idx] = fsrc[idx];
    const unsigned long long* bsrc = bitmapD + (size_t)b*BPB;
    if (tid < BPB) sbm[tid] = bsrc[tid];
  }

  // shared prologue: wave w computes channels {w, w+4, w+8, ...} (<=18), once
  {
    int a   = cellc / NPIX;
    int rem = cellc - a*NPIX;
    int jj  = rem / NWW;
    int ii  = rem - jj*NWW;
    const float* cb = outp + (((size_t)b*NANC + a)*CHC)*NPIX + rem;
    for (int ch = w; ch <= 18; ch += 4){
      float raw = cb[(size_t)ch * NPIX];
      if (ch == 18){
        sCf[lane] = sigmoidf_(raw);
      } else {
        int k = ch >> 1, axis = ch & 1;
        float r = (k == 0) ? sigmoidf_(raw) : raw;
        float v = axis ? (r + (float)jj) * SYH : (r + (float)ii) * SXW;
        float* dst = axis ? (float*)sPy : (float*)sPx;
        dst[(((k >> 1)*64) + lane)*2 + (k & 1)] = v;   // pair-major, slot k&1
      }
    }
  }
  __syncthreads();

  // bin-test phase: 9 corners, 1 LDS bit test each, rare global mask gather
  const unsigned long long* mbase = masksD + (size_t)b*MPB;
  int nv = nvalid[b];
  unsigned long long vmask = (nv >= 64) ? ~0ull : ((1ull << nv) - 1ull);
  unsigned long long qbits = 0ull;
#pragma unroll
  for (int p = 0; p < 5; ++p){
    f2 px = sPx[p*64 + lane];
    f2 py = sPy[p*64 + lane];
    {
      int k  = 2*p;
      int bx = min(max((int)floorf(px.x * BININV), 0), BINNX-1);
      int by = min(max((int)floorf(py.x * BININV), 0), BINNY-1);
      if ((sbm[k*BINNY + by] >> bx) & 1ull)
        qbits |= mbase[((size_t)(k*BINNY + by))*BINNX + bx];
    }
    if (p < 4){
      int k  = 2*p + 1;
      int bx = min(max((int)floorf(px.y * BININV), 0), BINNX-1);
      int by = min(max((int)floorf(py.y * BININV), 0), BINNY-1);
      if ((sbm[k*BINNY + by] >> bx) & 1ull)
        qbits |= mbase[((size_t)(k*BINNY + by))*BINNX + bx];
    }
  }
  qbits &= vmask;

  // wave-prefix push into the queue (one atomicAdd per wave)
  {
    int n = __popcll(qbits);
    int pref = n;
#pragma unroll
    for (int o = 1; o < 64; o <<= 1){
      int v = __shfl_up(pref, o, 64);
      if (lane >= o) pref += v;
    }
    int tot  = __shfl(pref, 63, 64);
    int excl = pref - n;
    int wbase = 0;
    if (lane == 63 && tot > 0) wbase = atomicAdd(&qcount, tot);
    wbase = __shfl(wbase, 63, 64);
    int slot = wbase + excl;
    unsigned long long qb = qbits;
    while (qb){
      int t = __ffsll((long long)qb) - 1;
      qb &= qb - 1;
      qlist[slot++] = (unsigned short)(lane | (t << 6));
    }
  }
  __syncthreads();

  // drain the queue: one candidate per thread per pass, full lane efficiency
  int n = qcount;
  for (int idx = tid; idx < n; idx += 256){
    unsigned int pkid = qlist[idx];
    int l2 = pkid & 63;
    int t  = pkid >> 6;
    const float* gg = sgt + t*GTS;
    float s = 0.0f;
#pragma unroll
    for (int p = 0; p < 5; ++p){
      f2 px = sPx[p*64 + l2];
      f2 py = sPy[p*64 + l2];
      {
        float dx = px.x + gg[2*p];
        float dy = py.x + gg[10 + 2*p];
        float d  = fast_sqrt(fmaf(dy, dy, dx*dx));   // identical to ref math
        float e  = fast_exp2(fmaf(d, -K2C, K1C));
        s += fmaxf(e, 1.0f);
      }
      if (p < 4){
        float dx = px.y + gg[2*p + 1];
        float dy = py.y + gg[10 + 2*p + 1];
        float d  = fast_sqrt(fmaf(dy, dy, dx*dx));
        float e  = fast_exp2(fmaf(d, -K2C, K1C));
        s += fmaxf(e, 1.0f);
      }
    }
    if (s > THRESH_S) atomicOr(&sexclw[l2 >> 5], 1u << (l2 & 31));
  }
  __syncthreads();

  if (w == 0){
    unsigned int ex = sexclw[lane >> 5];
    int m0 = ((ex >> (lane & 31)) & 1u) ? 0 : 1;
    float cf = sCf[lane];
    float contrib = (m0 && live) ? 0.5f*cf*cf : 0.0f;

    // bit-packed mask write: cellbase is 64-aligned
    unsigned long long mb = __ballot(m0 != 0);
    if ((lane & 31) == 0){
      unsigned int wv = (lane == 0) ? (unsigned int)mb : (unsigned int)(mb >> 32);
      maskw[(size_t)b*MWPB + (cellbase >> 5) + (lane >> 5)] = wv;
    }

    // wave reduce -> one double partial per block (deterministic, no atomics)
#pragma unroll
    for (int o = 32; o > 0; o >>= 1) contrib += __shfl_xor(contrib, o, 64);
    if (lane == 0)
      partials[(size_t)b*NBLKX + blockIdx.x] = (double)contrib;
  }
}

// ---------------- phase B+C: per-target values, scatter winners, small losses ----------------
__global__ __launch_bounds__(64) void scatter_loss_kernel(
    const float* __restrict__ outp, const float* __restrict__ tgt,
    const int* __restrict__ nvalid, const unsigned int* __restrict__ maskw,
    double* __restrict__ bc_part){
  int b = blockIdx.x;
  int t = threadIdx.x;                  // 0..63, targets are 0..49
  __shared__ int keys[NTT];
  int nv = nvalid[b];
  bool valid = (t < nv);

  int key = -1, gi0 = 0, gj0 = 0, bn = 0;
  float txv[KK], tyv[KK];
  float conf_t = 0.0f, tcls = 0.0f;

  if (t < NTT){
    const float* trow = tgt + ((size_t)b*NTT + t)*LL;
    tcls = trow[0];
    float gx0 = trow[1]*(float)NWW;
    float gy0 = trow[2]*(float)NHH;
    gi0 = min(max((int)floorf(gx0), 0), NWW-1);
    gj0 = min(max((int)floorf(gy0), 0), NHH-1);
#pragma unroll
    for (int k = 0; k < KK; ++k){
      txv[k] = trow[1+2*k]*(float)NWW - (float)gi0;
      tyv[k] = trow[2+2*k]*(float)NHH - (float)gj0;
    }
    // best anchor by IoU (first max wins)
    float gw = trow[LL-2]*(float)NWW, gh = trow[LL-1]*(float)NHH;
    float best = -1.0f;
    for (int a = 0; a < NANC; ++a){
      float aw = c_anch[2*a], ah = c_anch[2*a+1];
      float inter = fminf(aw, gw) * fminf(ah, gh);
      float iou = inter / (aw*ah + gw*gh - inter);
      if (iou > best){ best = iou; bn = a; }
    }
    key = bn*NPIX + gj0*NWW + gi0;
    keys[t] = key;

    // conf_t from pred_box at the wrapped flat index (reference's mod arithmetic)
    long f = (long)b*NANCHT - NPIX + gj0*NWW + gi0;
    if (f < 0) f += NCELLT;
    int bb  = (int)(f / NANCHT);
    int rr  = (int)(f - (long)bb*NANCHT);
    int aa  = rr / NPIX;
    int rr2 = rr - aa*NPIX;
    int jj  = rr2 / NWW;
    int ii  = rr2 - jj*NWW;
    const float* pbase = outp + (((size_t)bb*NANC + aa)*CHC)*NPIX + rr2;
    float s = 0.0f;
#pragma unroll
    for (int k = 0; k < KK; ++k){
      float rx = pbase[(2*k)*NPIX], ry = pbase[(2*k+1)*NPIX];
      if (k == 0){ rx = sigmoidf_(rx); ry = sigmoidf_(ry); }
      float Pxx = (rx + (float)ii)*SXW, Pyy = (ry + (float)jj)*SYH;
      float dx = Pxx - trow[1+2*k]*640.0f;
      float dy = Pyy - trow[2+2*k]*480.0f;
      float d  = fast_sqrt(fmaf(dy, dy, dx*dx));
      float e  = fast_exp2(fmaf(d, -K2C, K1C));
      s += fmaxf(e, 1.0f);
    }
    conf_t = (s - 9.0f) * CONF_T_SCALE;
  }
  __syncthreads();

  // winner = last valid t writing this (bn,gj,gi) cell (scan overwrite semantics)
  bool winner = valid;
  if (valid){
    for (int u = t+1; u < nv; ++u) if (keys[u] == key){ winner = false; break; }
  }

  double lx = 0.0, ly = 0.0, lcls = 0.0, lcf = 0.0;
  if (winner){
    const float* cbase = outp + (((size_t)b*NANC + bn)*CHC)*NPIX + gj0*NWW + gi0;
    float sx = 0.0f, sy = 0.0f;
#pragma unroll
    for (int k = 0; k < KK; ++k){
      float rx = cbase[(2*k)*NPIX], ry = cbase[(2*k+1)*NPIX];
      if (k == 0){ rx = sigmoidf_(rx); ry = sigmoidf_(ry); }
      float dx = rx - txv[k], dy = ry - tyv[k];
      sx = fmaf(dx, dx, sx); sy = fmaf(dy, dy, sy);
    }
    lx = 0.5*(double)sx; ly = 0.5*(double)sy;

    // class CE (log_softmax over 13 logits)
    float lg[NCLS], mx = -1e30f;
#pragma unroll
    for (int c = 0; c < NCLS; ++c){ lg[c] = cbase[(2*KK+1+c)*NPIX]; mx = fmaxf(mx, lg[c]); }
    float se = 0.0f;
#pragma unroll
    for (int c = 0; c < NCLS; ++c) se += fast_exp2((lg[c]-mx)*LOG2E_F);
    int label = min(max((int)tcls, 0), NCLS-1);
    lcls = (double)(mx + logf(se) - lg[label]);

    // conf-loss correction at object cell: + 0.5*OBJ*(conf-conf_t)^2 - base term
    float cf = sigmoidf_(cbase[(2*KK)*NPIX]);
    int idx = bn*NPIX + gj0*NWW + gi0;
    int m0 = (maskw[(size_t)b*MWPB + (idx >> 5)] >> (idx & 31)) & 1;
    float dcf = cf - conf_t;
    lcf = 0.5*OBJ_W*(double)(dcf*dcf) - (m0 ? 0.5*(double)(cf*cf) : 0.0);
  }

  // single-wave block: shfl reduce doubles, write per-batch partials
#pragma unroll
  for (int o = 32; o > 0; o >>= 1){
    lx  += __shfl_xor(lx,  o, 64);
    ly  += __shfl_xor(ly,  o, 64);
    lcls+= __shfl_xor(lcls,o, 64);
    lcf += __shfl_xor(lcf, o, 64);
  }
  if (threadIdx.x == 0){
    double* bp = bc_part + (size_t)b*4;
    bp[0] = lx; bp[1] = ly; bp[2] = lcls; bp[3] = lcf;
  }
}

// ---------------- finalize: deterministic reduce + epoch gate ----------------
__global__ __launch_bounds__(256) void finalize_kernel(
    const double* __restrict__ bc_part, const double* __restrict__ partials,
    const int* __restrict__ epoch_p, float* __restrict__ outv){
  int tid = threadIdx.x;
  double vx=0, vy=0, vc=0, vf=0, vb=0;
  for (int i = tid; i < NBB; i += 256){
    vx += bc_part[4*i]; vy += bc_part[4*i+1];
    vc += bc_part[4*i+2]; vf += bc_part[4*i+3];
  }
  for (int i = tid; i < NBLKX*NBB; i += 256) vb += partials[i];
#pragma unroll
  for (int o = 32; o > 0; o >>= 1){
    vx += __shfl_xor(vx, o, 64); vy += __shfl_xor(vy, o, 64);
    vc += __shfl_xor(vc, o, 64); vf += __shfl_xor(vf, o, 64);
    vb += __shfl_xor(vb, o, 64);
  }
  __shared__ double sm[5][4];
  int wid = tid >> 6, lane = tid & 63;
  if (lane == 0){ sm[0][wid]=vx; sm[1][wid]=vy; sm[2][wid]=vc; sm[3][wid]=vf; sm[4][wid]=vb; }
  __syncthreads();
  if (tid == 0){
    double fx=0, fy=0, fc=0, ff=0, fb=0;
    for (int w = 0; w < 4; ++w){ fx+=sm[0][w]; fy+=sm[1][w]; fc+=sm[2][w]; ff+=sm[3][w]; fb+=sm[4][w]; }
    double loss = fx + fy + fc;
    if (*epoch_p > EPOCH_PRETRAIN) loss += ff + fb;
    outv[0] = (float)loss;
  }
}

extern "C" void kernel_launch(void* const* d_in, const int* in_sizes, int n_in,
                              void* d_out, int out_size, void* d_ws, size_t ws_size,
                              hipStream_t stream){
  (void)in_sizes; (void)n_in; (void)out_size; (void)ws_size;
  const float* outp = (const float*)d_in[0];
  const float* tgt  = (const float*)d_in[1];
  const int*   ep   = (const int*)d_in[2];
  float* outv = (float*)d_out;
  char* ws = (char*)d_ws;

  double* bc_part  = (double*)(ws);                   // 4096 B
  double* partials = (double*)(ws + 4096);            // 54272 B
  float*  gts_neg  = (float*) (ws + 58368);           // 512000 B
  int*    nvalid   = (int*)   (ws + 570368);          // 512 B
  unsigned int* maskw = (unsigned int*)(ws + 570880); // 54272 B
  unsigned long long* masksD  = (unsigned long long*)(ws + 625152);  // 7,833,600 B
  unsigned long long* bitmapD = (unsigned long long*)(ws + 8458752); // 230,400 B

  // zero the bin tables (re-poisoned each iteration): masks + bitmap contiguous
  hipMemsetAsync(ws + 625152, 0, (size_t)NBB*MPB*8 + (size_t)NBB*BPB*8, stream);

  prep_kernel<<<dim3(NBB), dim3(256), 0, stream>>>(tgt, gts_neg, masksD, bitmapD, nvalid);
  region_confmask_kernel<<<dim3(NBLKX, NBB), dim3(256), 0, stream>>>(outp, gts_neg, masksD, bitmapD, nvalid, maskw, partials);
  scatter_loss_kernel<<<dim3(NBB), dim3(64), 0, stream>>>(outp, tgt, nvalid, maskw, bc_part);
  finalize_kernel<<<dim3(1), dim3(256), 0, stream>>>(bc_part, partials, ep, outv);
}

// Round 7
// 141.804 us; speedup vs baseline: 1.2679x; 1.2679x over previous
//
#include <hip/hip_runtime.h>
#include <math.h>
#include <stdint.h>

// ---------------- problem constants ----------------
#define KK     9     // corners
#define NCLS   13
#define NANC   5     // anchors
#define NBB    128
#define NHH    26
#define NWW    26
#define NTT    50    // targets
#define LL     21    // 2K+3
#define CHC    32    // 2K+1+NC channels per anchor
#define NPIX   676   // NH*NW
#define NANCHT 3380  // NA*NPIX
#define NCELLT 432640 // NB*NANCHT
#define GTS    20    // floats per target in packed gt layout
#define MWPB   106   // mask words per batch (ceil(3380/32) padded)
#define GTH_W  12    // dwords per target in f16 table (48B stride, 16B aligned)
#define NBLKX  7     // ceil(NANCHT/512) cell-groups per batch (512 cells/block)

// derived float constants (computed in double, rounded once)
#define LOG2E_F   1.4426950408889634f
#define K1C       2.8853900817779268f   // SHARP*log2e
#define K2C       0.036067376022224085f // K1C/TH
#define SXW       24.615384615384617f   // 640/26
#define SYH       18.461538461538463f   // 480/26
#define THRESH_S  43.500902934225507f   // 9 + SIL*9*(e^2-1)
#define CONF_T_SCALE 0.017390849194407297f // (1/(e^2-1))/9
#define OBJ_W     5.0f
#define EPOCH_PRETRAIN 15
#define BIGV      6.0e18f               // pad sentinel: converts to +inf in f16 (safe in pk ops)

// f16 cull (first-min): coords scaled by 1/32 (max ~25 units). RN f32->f16 err
// <= 0.39px/operand -> |d_hat-d| <= ~1.1px; exact boundary d*=16.98px needs
// d_hat^2 < ((16.98+1.2)/32)^2 = 0.323. Threshold 0.36 covers RTZ-everywhere.
// Conservative-only: exact f32 path re-verifies with reference-identical math.
#define CULL_H2   0.36f
#define HSCALE    0.03125f              // 1/32, exact power of 2

typedef __attribute__((ext_vector_type(2))) float f2;
typedef __attribute__((ext_vector_type(2))) _Float16 h2;
typedef __attribute__((ext_vector_type(4))) unsigned int u4;
typedef __attribute__((ext_vector_type(2))) unsigned int u2;

static __device__ __forceinline__ float fast_exp2(float x){
  return __builtin_amdgcn_exp2f(x);
}
static __device__ __forceinline__ float fast_sqrt(float x){
  return __builtin_amdgcn_sqrtf(x);
}
static __device__ __forceinline__ float sigmoidf_(float x){
  return 1.0f/(1.0f + fast_exp2(-LOG2E_F*x));
}

__constant__ float c_anch[10] = {1.482f,2.2412f,2.0501f,3.1265f,2.3946f,4.6891f,
                                 3.1018f,3.991f,3.4879f,5.8851f};

// ws layout (bytes):
//   [0,4096)         : bc_part  double[NBB][4]
//   [4096,18432)     : partials double[NBB*NBLKX] (896 used)
//   [18432,530432)   : gts_neg  float[NBB*NTT*GTS]  packed NEGATED px corners (f32):
//                        per (b,t): [x0..x8, BIG, y0..y8, BIG]
//   [530432,530944)  : nvalid   int[NBB]
//   [530944,585216)  : maskw    u32[NBB*MWPB]       bit-packed conf_mask0
//   [585216,892416)  : gth      u32[NBB*NTT*12]     packed-f16 NEGATED scaled corners:
//                        per (b,t): w0..4 x-pairs (x8,inf), w5..9 y-pairs (y8,inf), w10..11 inf

// ---------------- phase 0: prep (ballot nv; f32 + f16 gt tables) ----------------
__global__ __launch_bounds__(64) void prep_kernel(const float* __restrict__ tgt,
                                                  float* __restrict__ gts_neg,
                                                  unsigned int* __restrict__ gth,
                                                  int* __restrict__ nvalid){
  int b = blockIdx.x;
  int t = threadIdx.x;                          // one wave
  const float* trow = tgt + (size_t)b*NTT*LL;
  float v1 = (t < NTT) ? trow[t*LL + 1] : 0.0f;
  unsigned long long mk = __ballot(t < NTT && v1 != 0.0f);
  int firstInvalid = __ffsll(~mk) - 1;          // prefix length (cumprod semantics)
  if (t == 0) nvalid[b] = firstInvalid;
  for (int idx = t; idx < NTT*GTS; idx += 64){
    int tt = idx / GTS;
    int c  = idx - tt*GTS;
    float v;
    if (c == 9 || c == 19)      v = BIGV;
    else if (c < 9)             v = -(trow[tt*LL + 1 + 2*c] * 640.0f);
    else                        v = -(trow[tt*LL + 2 + 2*(c-10)] * 480.0f);
    gts_neg[(size_t)b*NTT*GTS + idx] = v;
  }
  // f16 table: value = -(coord_px)/32  (x: trow*640/32 = trow*20; y: trow*15)
  for (int idx = t; idx < NTT*GTH_W; idx += 64){
    int tt = idx / GTH_W;
    int w  = idx - tt*GTH_W;
    const float* tr2 = trow + tt*LL;
    float a0 = BIGV, a1 = BIGV;
    if (w < 5){
      int k0 = 2*w;
      a0 = -(tr2[1 + 2*k0] * 20.0f);
      if (k0 + 1 < KK) a1 = -(tr2[1 + 2*(k0+1)] * 20.0f);
    } else if (w < 10){
      int k0 = 2*(w-5);
      a0 = -(tr2[2 + 2*k0] * 15.0f);
      if (k0 + 1 < KK) a1 = -(tr2[2 + 2*(k0+1)] * 15.0f);
    }
    h2 hh; hh.x = (_Float16)a0; hh.y = (_Float16)a1;   // BIGV -> +inf
    gth[(size_t)b*NTT*GTH_W + idx] = __builtin_bit_cast(unsigned int, hh);
  }
}

// ---------------- phase A: R1 structure, 2 cells per lane ----------------
// Block = 512 cells, 4 waves; lane owns cells (base + w*64 + lane) and (+256).
// Identical f16 cull + exact f32 path as the best-measured R1 kernel; the 3
// per-target LDS broadcasts and loop bookkeeping now serve 128 cells/wave, and
// wave count halves at equal effective occupancy (R1 measured ~3.6/SIMD).
__global__ __launch_bounds__(256) void region_confmask_kernel(
    const float* __restrict__ outp, const float* __restrict__ gts_neg,
    const unsigned int* __restrict__ gth,
    const int* __restrict__ nvalid, unsigned int* __restrict__ maskw,
    double* __restrict__ partials){
  int b    = blockIdx.y;
  int tid  = threadIdx.x;
  int lane = tid & 63;
  int w    = tid >> 6;
  int waveA = blockIdx.x * 512 + w*64;          // 64-aligned base of A-cells
  int waveB = waveA + 256;                      // 64-aligned base of B-cells
  int cA = waveA + lane;
  int cB = waveB + lane;
  bool liveA = (cA < NANCHT);
  bool liveB = (cB < NANCHT);
  int cAc = liveA ? cA : (NANCHT-1);
  int cBc = liveB ? cB : (NANCHT-1);

  __shared__ float sgt[NTT*GTS] __attribute__((aligned(16)));          // 4000 B f32
  __shared__ unsigned int sgh[NTT*GTH_W] __attribute__((aligned(16))); // 2400 B f16
  {
    const float* fsrc = gts_neg + (size_t)b*NTT*GTS;
    for (int idx = tid; idx < NTT*GTS; idx += 256) sgt[idx] = fsrc[idx];
    const unsigned int* gsrc = gth + (size_t)b*NTT*GTH_W;
    for (int idx = tid; idx < NTT*GTH_W; idx += 256) sgh[idx] = gsrc[idx];
  }
  __syncthreads();

  // per-cell prologue (x2): f32 corners + f16 scaled corners
  f2 PxpA[5], PypA[5], PxpB[5], PypB[5];
  h2 PxhA[5], PyhA[5], PxhB[5], PyhB[5];
  const float* baseA;
  const float* baseB;
  {
    int a   = cAc / NPIX;
    int rem = cAc - a*NPIX;
    int j   = rem / NWW;
    int i   = rem - j*NWW;
    baseA = outp + (((size_t)b*NANC + a)*CHC)*NPIX + rem;
#pragma unroll
    for (int k = 0; k < KK; ++k){
      float rx = baseA[(2*k)*NPIX];
      float ry = baseA[(2*k+1)*NPIX];
      if (k == 0){ rx = sigmoidf_(rx); ry = sigmoidf_(ry); }
      PxpA[k>>1][k&1] = (rx + (float)i) * SXW;
      PypA[k>>1][k&1] = (ry + (float)j) * SYH;
    }
    PxpA[4][1] = 0.0f; PypA[4][1] = 0.0f;
  }
  {
    int a   = cBc / NPIX;
    int rem = cBc - a*NPIX;
    int j   = rem / NWW;
    int i   = rem - j*NWW;
    baseB = outp + (((size_t)b*NANC + a)*CHC)*NPIX + rem;
#pragma unroll
    for (int k = 0; k < KK; ++k){
      float rx = baseB[(2*k)*NPIX];
      float ry = baseB[(2*k+1)*NPIX];
      if (k == 0){ rx = sigmoidf_(rx); ry = sigmoidf_(ry); }
      PxpB[k>>1][k&1] = (rx + (float)i) * SXW;
      PypB[k>>1][k&1] = (ry + (float)j) * SYH;
    }
    PxpB[4][1] = 0.0f; PypB[4][1] = 0.0f;
  }
#pragma unroll
  for (int p = 0; p < 5; ++p){
    PxhA[p].x = (_Float16)(PxpA[p].x * HSCALE);
    PxhA[p].y = (_Float16)(PxpA[p].y * HSCALE);
    PyhA[p].x = (_Float16)(PypA[p].x * HSCALE);
    PyhA[p].y = (_Float16)(PypA[p].y * HSCALE);
    PxhB[p].x = (_Float16)(PxpB[p].x * HSCALE);
    PxhB[p].y = (_Float16)(PxpB[p].y * HSCALE);
    PyhB[p].x = (_Float16)(PypB[p].x * HSCALE);
    PyhB[p].y = (_Float16)(PypB[p].y * HSCALE);
  }

  int nv = nvalid[b];                           // wave-uniform
  const _Float16 thh = (_Float16)CULL_H2;
  unsigned long long qbitsA = 0ull, qbitsB = 0ull;
#pragma unroll 2
  for (int t = 0; t < nv; ++t){
    const u4* q = (const u4*)(sgh + t*GTH_W);   // wave-uniform LDS broadcast
    u4 q0 = q[0];
    u4 q1 = q[1];
    u2 q2 = *(const u2*)(sgh + t*GTH_W + 8);
    h2 Xa[5] = { __builtin_bit_cast(h2, q0.x), __builtin_bit_cast(h2, q0.y),
                 __builtin_bit_cast(h2, q0.z), __builtin_bit_cast(h2, q0.w),
                 __builtin_bit_cast(h2, q1.x) };
    h2 Ya[5] = { __builtin_bit_cast(h2, q1.y), __builtin_bit_cast(h2, q1.z),
                 __builtin_bit_cast(h2, q1.w), __builtin_bit_cast(h2, q2.x),
                 __builtin_bit_cast(h2, q2.y) };
    h2 m2A = {(_Float16)60000.0f, (_Float16)60000.0f};
    h2 m2B = {(_Float16)60000.0f, (_Float16)60000.0f};
#pragma unroll
    for (int p = 0; p < 5; ++p){
      h2 dxA = PxhA[p] + Xa[p];                 // v_pk_add_f16 (gt pre-negated)
      h2 dyA = PyhA[p] + Ya[p];
      h2 rA  = __builtin_elementwise_fma(dyA, dyA, dxA*dxA);
      m2A = __builtin_elementwise_min(m2A, rA);
      h2 dxB = PxhB[p] + Xa[p];
      h2 dyB = PyhB[p] + Ya[p];
      h2 rB  = __builtin_elementwise_fma(dyB, dyB, dxB*dxB);
      m2B = __builtin_elementwise_min(m2B, rB);
    }
    _Float16 mmA = (m2A.x < m2A.y) ? m2A.x : m2A.y;
    _Float16 mmB = (m2B.x < m2B.y) ? m2B.x : m2B.y;
    if (mmA < thh) qbitsA |= (1ull << t);
    if (mmB < thh) qbitsB |= (1ull << t);
  }

  int m0A = 1, m0B = 1;
  if (__any((qbitsA | qbitsB) != 0ull)){        // exact f32 path for near pairs
    bool excA = false, excB = false;
    while (qbitsA){
      int t = __ffsll((long long)qbitsA) - 1;
      qbitsA &= qbitsA - 1;
      const float* gg = sgt + t*GTS;
      float s = 0.0f;
#pragma unroll
      for (int k = 0; k < KK; ++k){
        float dx = PxpA[k>>1][k&1] + gg[k];
        float dy = PypA[k>>1][k&1] + gg[10+k];
        float d  = fast_sqrt(fmaf(dy, dy, dx*dx));   // identical to ref math
        float e  = fast_exp2(fmaf(d, -K2C, K1C));
        s += fmaxf(e, 1.0f);
      }
      excA |= (s > THRESH_S);
    }
    while (qbitsB){
      int t = __ffsll((long long)qbitsB) - 1;
      qbitsB &= qbitsB - 1;
      const float* gg = sgt + t*GTS;
      float s = 0.0f;
#pragma unroll
      for (int k = 0; k < KK; ++k){
        float dx = PxpB[k>>1][k&1] + gg[k];
        float dy = PypB[k>>1][k&1] + gg[10+k];
        float d  = fast_sqrt(fmaf(dy, dy, dx*dx));
        float e  = fast_exp2(fmaf(d, -K2C, K1C));
        s += fmaxf(e, 1.0f);
      }
      excB |= (s > THRESH_S);
    }
    if (excA) m0A = 0;
    if (excB) m0B = 0;
  }

  float cfA = sigmoidf_(baseA[(2*KK)*NPIX]);
  float cfB = sigmoidf_(baseB[(2*KK)*NPIX]);
  float contrib = ((m0A && liveA) ? 0.5f*cfA*cfA : 0.0f)
                + ((m0B && liveB) ? 0.5f*cfB*cfB : 0.0f);

  // bit-packed mask writes: one ballot per cell-group, two u32 stores each
  unsigned long long mbA = __ballot(m0A != 0);
  unsigned long long mbB = __ballot(m0B != 0);
  if ((lane & 31) == 0){
    if (waveA < NANCHT){
      unsigned int wv = (lane == 0) ? (unsigned int)mbA : (unsigned int)(mbA >> 32);
      maskw[(size_t)b*MWPB + (waveA >> 5) + (lane >> 5)] = wv;
    }
    if (waveB < NANCHT){
      unsigned int wv = (lane == 0) ? (unsigned int)mbB : (unsigned int)(mbB >> 32);
      maskw[(size_t)b*MWPB + (waveB >> 5) + (lane >> 5)] = wv;
    }
  }

  // block reduce -> one double partial per block (deterministic, no atomics)
#pragma unroll
  for (int o = 32; o > 0; o >>= 1) contrib += __shfl_xor(contrib, o, 64);
  __shared__ float wsum[4];
  int wid = tid >> 6;
  if (lane == 0) wsum[wid] = contrib;
  __syncthreads();
  if (tid == 0){
    double tot = (double)wsum[0] + (double)wsum[1] + (double)wsum[2] + (double)wsum[3];
    partials[blockIdx.y * gridDim.x + blockIdx.x] = tot;
  }
}

// ---------------- phase B+C: per-target values, scatter winners, small losses ----------------
__global__ __launch_bounds__(64) void scatter_loss_kernel(
    const float* __restrict__ outp, const float* __restrict__ tgt,
    const int* __restrict__ nvalid, const unsigned int* __restrict__ maskw,
    double* __restrict__ bc_part){
  int b = blockIdx.x;
  int t = threadIdx.x;                  // 0..63, targets are 0..49
  __shared__ int keys[NTT];
  int nv = nvalid[b];
  bool valid = (t < nv);

  int key = -1, gi0 = 0, gj0 = 0, bn = 0;
  float txv[KK], tyv[KK];
  float conf_t = 0.0f, tcls = 0.0f;

  if (t < NTT){
    const float* trow = tgt + ((size_t)b*NTT + t)*LL;
    tcls = trow[0];
    float gx0 = trow[1]*(float)NWW;
    float gy0 = trow[2]*(float)NHH;
    gi0 = min(max((int)floorf(gx0), 0), NWW-1);
    gj0 = min(max((int)floorf(gy0), 0), NHH-1);
#pragma unroll
    for (int k = 0; k < KK; ++k){
      txv[k] = trow[1+2*k]*(float)NWW - (float)gi0;
      tyv[k] = trow[2+2*k]*(float)NHH - (float)gj0;
    }
    // best anchor by IoU (first max wins)
    float gw = trow[LL-2]*(float)NWW, gh = trow[LL-1]*(float)NHH;
    float best = -1.0f;
    for (int a = 0; a < NANC; ++a){
      float aw = c_anch[2*a], ah = c_anch[2*a+1];
      float inter = fminf(aw, gw) * fminf(ah, gh);
      float iou = inter / (aw*ah + gw*gh - inter);
      if (iou > best){ best = iou; bn = a; }
    }
    key = bn*NPIX + gj0*NWW + gi0;
    keys[t] = key;

    // conf_t from pred_box at the wrapped flat index (reference's mod arithmetic)
    long f = (long)b*NANCHT - NPIX + gj0*NWW + gi0;
    if (f < 0) f += NCELLT;
    int bb  = (int)(f / NANCHT);
    int rr  = (int)(f - (long)bb*NANCHT);
    int aa  = rr / NPIX;
    int rr2 = rr - aa*NPIX;
    int jj  = rr2 / NWW;
    int ii  = rr2 - jj*NWW;
    const float* pbase = outp + (((size_t)bb*NANC + aa)*CHC)*NPIX + rr2;
    float s = 0.0f;
#pragma unroll
    for (int k = 0; k < KK; ++k){
      float rx = pbase[(2*k)*NPIX], ry = pbase[(2*k+1)*NPIX];
      if (k == 0){ rx = sigmoidf_(rx); ry = sigmoidf_(ry); }
      float Pxx = (rx + (float)ii)*SXW, Pyy = (ry + (float)jj)*SYH;
      float dx = Pxx - trow[1+2*k]*640.0f;
      float dy = Pyy - trow[2+2*k]*480.0f;
      float d  = fast_sqrt(fmaf(dy, dy, dx*dx));
      float e  = fast_exp2(fmaf(d, -K2C, K1C));
      s += fmaxf(e, 1.0f);
    }
    conf_t = (s - 9.0f) * CONF_T_SCALE;
  }
  __syncthreads();

  // winner = last valid t writing this (bn,gj,gi) cell (scan overwrite semantics)
  bool winner = valid;
  if (valid){
    for (int u = t+1; u < nv; ++u) if (keys[u] == key){ winner = false; break; }
  }

  double lx = 0.0, ly = 0.0, lcls = 0.0, lcf = 0.0;
  if (winner){
    const float* cbase = outp + (((size_t)b*NANC + bn)*CHC)*NPIX + gj0*NWW + gi0;
    float sx = 0.0f, sy = 0.0f;
#pragma unroll
    for (int k = 0; k < KK; ++k){
      float rx = cbase[(2*k)*NPIX], ry = cbase[(2*k+1)*NPIX];
      if (k == 0){ rx = sigmoidf_(rx); ry = sigmoidf_(ry); }
      float dx = rx - txv[k], dy = ry - tyv[k];
      sx = fmaf(dx, dx, sx); sy = fmaf(dy, dy, sy);
    }
    lx = 0.5*(double)sx; ly = 0.5*(double)sy;

    // class CE (log_softmax over 13 logits)
    float lg[NCLS], mx = -1e30f;
#pragma unroll
    for (int c = 0; c < NCLS; ++c){ lg[c] = cbase[(2*KK+1+c)*NPIX]; mx = fmaxf(mx, lg[c]); }
    float se = 0.0f;
#pragma unroll
    for (int c = 0; c < NCLS; ++c) se += fast_exp2((lg[c]-mx)*LOG2E_F);
    int label = min(max((int)tcls, 0), NCLS-1);
    lcls = (double)(mx + logf(se) - lg[label]);

    // conf-loss correction at object cell: + 0.5*OBJ*(conf-conf_t)^2 - base term
    float cf = sigmoidf_(cbase[(2*KK)*NPIX]);
    int idx = bn*NPIX + gj0*NWW + gi0;
    int m0 = (maskw[(size_t)b*MWPB + (idx >> 5)] >> (idx & 31)) & 1;
    float dcf = cf - conf_t;
    lcf = 0.5*OBJ_W*(double)(dcf*dcf) - (m0 ? 0.5*(double)(cf*cf) : 0.0);
  }

  // single-wave block: shfl reduce doubles, write per-batch partials
#pragma unroll
  for (int o = 32; o > 0; o >>= 1){
    lx  += __shfl_xor(lx,  o, 64);
    ly  += __shfl_xor(ly,  o, 64);
    lcls+= __shfl_xor(lcls,o, 64);
    lcf += __shfl_xor(lcf, o, 64);
  }
  if (threadIdx.x == 0){
    double* bp = bc_part + (size_t)b*4;
    bp[0] = lx; bp[1] = ly; bp[2] = lcls; bp[3] = lcf;
  }
}

// ---------------- finalize: deterministic reduce + epoch gate ----------------
__global__ __launch_bounds__(256) void finalize_kernel(
    const double* __restrict__ bc_part, const double* __restrict__ partials,
    const int* __restrict__ epoch_p, float* __restrict__ outv){
  int tid = threadIdx.x;
  double vx=0, vy=0, vc=0, vf=0, vb=0;
  for (int i = tid; i < NBB; i += 256){
    vx += bc_part[4*i]; vy += bc_part[4*i+1];
    vc += bc_part[4*i+2]; vf += bc_part[4*i+3];
  }
  for (int i = tid; i < NBLKX*NBB; i += 256) vb += partials[i];
#pragma unroll
  for (int o = 32; o > 0; o >>= 1){
    vx += __shfl_xor(vx, o, 64); vy += __shfl_xor(vy, o, 64);
    vc += __shfl_xor(vc, o, 64); vf += __shfl_xor(vf, o, 64);
    vb += __shfl_xor(vb, o, 64);
  }
  __shared__ double sm[5][4];
  int wid = tid >> 6, lane = tid & 63;
  if (lane == 0){ sm[0][wid]=vx; sm[1][wid]=vy; sm[2][wid]=vc; sm[3][wid]=vf; sm[4][wid]=vb; }
  __syncthreads();
  if (tid == 0){
    double fx=0, fy=0, fc=0, ff=0, fb=0;
    for (int w = 0; w < 4; ++w){ fx+=sm[0][w]; fy+=sm[1][w]; fc+=sm[2][w]; ff+=sm[3][w]; fb+=sm[4][w]; }
    double loss = fx + fy + fc;
    if (*epoch_p > EPOCH_PRETRAIN) loss += ff + fb;
    outv[0] = (float)loss;
  }
}

extern "C" void kernel_launch(void* const* d_in, const int* in_sizes, int n_in,
                              void* d_out, int out_size, void* d_ws, size_t ws_size,
                              hipStream_t stream){
  (void)in_sizes; (void)n_in; (void)out_size; (void)ws_size;
  const float* outp = (const float*)d_in[0];
  const float* tgt  = (const float*)d_in[1];
  const int*   ep   = (const int*)d_in[2];
  float* outv = (float*)d_out;
  char* ws = (char*)d_ws;

  double* bc_part  = (double*)(ws);                  // 4096 B
  double* partials = (double*)(ws + 4096);           // 14336 B
  float*  gts_neg  = (float*) (ws + 18432);          // 512000 B
  int*    nvalid   = (int*)   (ws + 530432);         // 512 B
  unsigned int* maskw = (unsigned int*)(ws + 530944); // 54272 B
  unsigned int* gth   = (unsigned int*)(ws + 585216); // 307200 B

  prep_kernel<<<dim3(NBB), dim3(64), 0, stream>>>(tgt, gts_neg, gth, nvalid);
  region_confmask_kernel<<<dim3(NBLKX, NBB), dim3(256), 0, stream>>>(outp, gts_neg, gth, nvalid, maskw, partials);
  scatter_loss_kernel<<<dim3(NBB), dim3(64), 0, stream>>>(outp, tgt, nvalid, maskw, bc_part);
  finalize_kernel<<<dim3(1), dim3(256), 0, stream>>>(bc_part, partials, ep, outv);
}

// Round 8
// 134.164 us; speedup vs baseline: 1.3401x; 1.0569x over previous
//
#include <hip/hip_runtime.h>
#include <math.h>

// ---------------- problem constants ----------------
#define KK     9     // corners
#define NCLS   13
#define NANC   5     // anchors
#define NBB    128
#define NHH    26
#define NWW    26
#define NTT    50    // targets
#define LL     21    // 2K+3
#define CHC    32    // 2K+1+NC channels per anchor
#define NPIX   676   // NH*NW
#define NANCHT 3380  // NA*NPIX
#define NCELLT 432640 // NB*NANCHT
#define GTS    20    // floats per target in packed gt layout
#define MWPB   106   // mask words per batch (ceil(3380/32) padded)

// derived float constants (computed in double, rounded once)
#define LOG2E_F   1.4426950408889634f
#define K1C       2.8853900817779268f   // SHARP*log2e
#define K2C       0.036067376022224085f // K1C/TH
#define SXW       24.615384615384617f   // 640/26
#define SYH       18.461538461538463f   // 480/26
#define THRESH_S  43.500902934225507f   // 9 + SIL*9*(e^2-1)
#define CONF_T_SCALE 0.017390849194407297f // (1/(e^2-1))/9
#define OBJ_W     5.0f
#define EPOCH_PRETRAIN 15
#define BIGV      6.0e18f               // pad sentinel: converts to +inf in f16 (safe in pk ops)

// f16 cull: coords scaled by 1/32 (max ~25 units). RN f32->f16 err <= 25*2^-11
// = 0.39px/operand -> |d_hat - d| <= ~1.1px; exact boundary d*=16.98px needs
// d_hat^2 < ((16.98+1.2)/32)^2 = 0.323. Threshold 0.36 (== d<19.2px) covers
// even RTZ-everywhere (0.359). Conservative-only: exact f32 path re-verifies.
#define CULL_H2   0.36f
#define HSCALE    0.03125f              // 1/32, exact power of 2

typedef __attribute__((ext_vector_type(2))) float f2;
typedef __attribute__((ext_vector_type(2))) _Float16 h2;
typedef __attribute__((ext_vector_type(4))) unsigned int u4;

static __device__ __forceinline__ float fast_exp2(float x){
  return __builtin_amdgcn_exp2f(x);
}
static __device__ __forceinline__ float fast_sqrt(float x){
  return __builtin_amdgcn_sqrtf(x);
}
static __device__ __forceinline__ float sigmoidf_(float x){
  return 1.0f/(1.0f + fast_exp2(-LOG2E_F*x));
}

__constant__ float c_anch[10] = {1.482f,2.2412f,2.0501f,3.1265f,2.3946f,4.6891f,
                                 3.1018f,3.991f,3.4879f,5.8851f};

// ws layout (bytes):
//   [0,4096)         : bc_part  double[NBB][4]
//   [4096,18432)     : partials double[1792]
//   [18432,530432)   : gts_neg  float[NBB*NTT*GTS]  packed NEGATED px corners:
//                        per (b,t): [x0..x8, BIG, y0..y8, BIG]
//   [530432,530944)  : nvalid   int[NBB]
//   [530944,585216)  : maskw   u32[NBB*MWPB]        bit-packed conf_mask0

// ---------------- phase 0: prep (ballot nv; packed negated gt corners) ----------------
__global__ __launch_bounds__(64) void prep_kernel(const float* __restrict__ tgt,
                                                  float* __restrict__ gts_neg,
                                                  int* __restrict__ nvalid){
  int b = blockIdx.x;
  int t = threadIdx.x;                          // one wave
  const float* trow = tgt + (size_t)b*NTT*LL;
  float v1 = (t < NTT) ? trow[t*LL + 1] : 0.0f;
  unsigned long long mk = __ballot(t < NTT && v1 != 0.0f);
  int firstInvalid = __ffsll(~mk) - 1;          // prefix length (cumprod semantics)
  if (t == 0) nvalid[b] = firstInvalid;
  for (int idx = t; idx < NTT*GTS; idx += 64){
    int tt = idx / GTS;
    int c  = idx - tt*GTS;
    float v;
    if (c == 9 || c == 19)      v = BIGV;
    else if (c < 9)             v = -(trow[tt*LL + 1 + 2*c] * 640.0f);
    else                        v = -(trow[tt*LL + 2 + 2*(c-10)] * 480.0f);
    gts_neg[(size_t)b*NTT*GTS + idx] = v;
  }
}

// ---------------- phase A: mask0 via packed-f16 cull + rare exact f32 path ----------------
__global__ __launch_bounds__(256) void region_confmask_kernel(
    const float* __restrict__ outp, const float* __restrict__ gts_neg,
    const int* __restrict__ nvalid, unsigned int* __restrict__ maskw,
    double* __restrict__ partials){
  int b = blockIdx.y;
  int cell = blockIdx.x * blockDim.x + threadIdx.x;   // 0..3379 within batch

  __shared__ float sgt[NTT*GTS] __attribute__((aligned(16)));   // 4000 B (f32, exact path)
  __shared__ h2   sgth[NTT*12] __attribute__((aligned(16)));    // 2400 B (f16 cull)
  const float* g32 = gts_neg + (size_t)b*NTT*GTS;
  for (int idx = threadIdx.x; idx < NTT*GTS; idx += 256)
    sgt[idx] = g32[idx];
  // f16 packed layout per target (12 h2 words, 48B stride, 16B aligned):
  //   w0..3: x pairs k=0..7 | w4: (x8, BIG) | w5..8: y pairs | w9: (y8, BIG) | w10,11: pad
  for (int widx = threadIdx.x; widx < NTT*12; widx += 256){
    int tt = widx / 12, w = widx - tt*12;
    float a0 = BIGV, a1 = BIGV;
    if (w < 10){ a0 = g32[tt*GTS + 2*w]; a1 = g32[tt*GTS + 2*w + 1]; }
    h2 hh;
    hh.x = (_Float16)(a0 * HSCALE);    // BIGV/32 -> +inf in f16 (pad sentinel)
    hh.y = (_Float16)(a1 * HSCALE);
    sgth[widx] = hh;
  }
  __syncthreads();

  int m0 = 1;
  float contrib = 0.0f;
  if (cell < NANCHT){
    int a   = cell / NPIX;
    int rem = cell - a*NPIX;
    int j   = rem / NWW;
    int i   = rem - j*NWW;
    const float* base = outp + (((size_t)b*NANC + a)*CHC)*NPIX + rem;

    f2 Pxp[5], Pyp[5];                 // f32 corners (exact path)
#pragma unroll
    for (int k = 0; k < KK; ++k){
      float rx = base[(2*k)*NPIX];
      float ry = base[(2*k+1)*NPIX];
      if (k == 0){ rx = sigmoidf_(rx); ry = sigmoidf_(ry); }
      Pxp[k>>1][k&1] = (rx + (float)i) * SXW;
      Pyp[k>>1][k&1] = (ry + (float)j) * SYH;
    }
    Pxp[4][1] = 0.0f; Pyp[4][1] = 0.0f;          // pad corner vs +inf sentinel

    h2 Pxh[5], Pyh[5];                 // f16 scaled corners (cull path)
#pragma unroll
    for (int p = 0; p < 5; ++p){
      Pxh[p].x = (_Float16)(Pxp[p].x * HSCALE);
      Pxh[p].y = (_Float16)(Pxp[p].y * HSCALE);
      Pyh[p].x = (_Float16)(Pyp[p].x * HSCALE);
      Pyh[p].y = (_Float16)(Pyp[p].y * HSCALE);
    }

    int nv = nvalid[b];                           // wave-uniform
    const _Float16 thh = (_Float16)CULL_H2;
    unsigned long long qbits = 0ull;
#pragma unroll 2
    for (int t = 0; t < nv; ++t){
      const u4* gh = (const u4*)(sgth + t*12);    // 3 b128-capable chunks
      u4 q0 = gh[0], q1 = gh[1], q2 = gh[2];
      h2 Xa[5] = { __builtin_bit_cast(h2, q0.x), __builtin_bit_cast(h2, q0.y),
                   __builtin_bit_cast(h2, q0.z), __builtin_bit_cast(h2, q0.w),
                   __builtin_bit_cast(h2, q1.x) };
      h2 Ya[5] = { __builtin_bit_cast(h2, q1.y), __builtin_bit_cast(h2, q1.z),
                   __builtin_bit_cast(h2, q1.w), __builtin_bit_cast(h2, q2.x),
                   __builtin_bit_cast(h2, q2.y) };
      h2 m2 = {(_Float16)60000.0f, (_Float16)60000.0f};
#pragma unroll
      for (int p = 0; p < 5; ++p){
        h2 dx = Pxh[p] + Xa[p];                   // v_pk_add_f16 (gt pre-negated)
        h2 dy = Pyh[p] + Ya[p];
        h2 r  = __builtin_elementwise_fma(dy, dy, dx*dx);  // pk_mul + pk_fma f16
        m2 = __builtin_elementwise_min(m2, r);
      }
      if (m2.x < thh || m2.y < thh) qbits |= (1ull << t);
    }

    if (__any(qbits != 0ull)){                    // exact f32 path for near pairs
      bool exc = false;
      while (qbits){
        int t = __ffsll((long long)qbits) - 1;
        qbits &= qbits - 1;
        const float* gg = sgt + t*GTS;
        float s = 0.0f;
#pragma unroll
        for (int k = 0; k < KK; ++k){
          float dx = Pxp[k>>1][k&1] + gg[k];
          float dy = Pyp[k>>1][k&1] + gg[10+k];
          float d  = fast_sqrt(fmaf(dy, dy, dx*dx));   // identical to ref math
          float e  = fast_exp2(fmaf(d, -K2C, K1C));
          s += fmaxf(e, 1.0f);
        }
        exc |= (s > THRESH_S);
      }
      if (exc) m0 = 0;
    }
    float cf = sigmoidf_(base[(2*KK)*NPIX]);
    contrib = m0 ? 0.5f*cf*cf : 0.0f;
  }

  // bit-packed mask write: one ballot per wave, two u32 stores
  unsigned long long mb = __ballot(m0 != 0);
  int lane = threadIdx.x & 63;
  int wavebase = blockIdx.x * 256 + (threadIdx.x & ~63);   // 64-aligned within batch
  if ((lane & 31) == 0 && wavebase < NANCHT){
    unsigned int w = (lane == 0) ? (unsigned int)mb : (unsigned int)(mb >> 32);
    maskw[(size_t)b*MWPB + (wavebase >> 5) + (lane >> 5)] = w;
  }

  // block reduce -> one double partial per block (deterministic, no atomics)
#pragma unroll
  for (int o = 32; o > 0; o >>= 1) contrib += __shfl_xor(contrib, o, 64);
  __shared__ float wsum[4];
  int wid = threadIdx.x >> 6;
  if (lane == 0) wsum[wid] = contrib;
  __syncthreads();
  if (threadIdx.x == 0){
    double tot = (double)wsum[0] + (double)wsum[1] + (double)wsum[2] + (double)wsum[3];
    partials[blockIdx.y * gridDim.x + blockIdx.x] = tot;
  }
}

// ---------------- phase B+C: per-target values, scatter winners, small losses ----------------
__global__ __launch_bounds__(64) void scatter_loss_kernel(
    const float* __restrict__ outp, const float* __restrict__ tgt,
    const int* __restrict__ nvalid, const unsigned int* __restrict__ maskw,
    double* __restrict__ bc_part){
  int b = blockIdx.x;
  int t = threadIdx.x;                  // 0..63, targets are 0..49
  __shared__ int keys[NTT];
  int nv = nvalid[b];
  bool valid = (t < nv);

  int key = -1, gi0 = 0, gj0 = 0, bn = 0;
  float txv[KK], tyv[KK];
  float conf_t = 0.0f, tcls = 0.0f;

  if (t < NTT){
    const float* trow = tgt + ((size_t)b*NTT + t)*LL;
    tcls = trow[0];
    float gx0 = trow[1]*(float)NWW;
    float gy0 = trow[2]*(float)NHH;
    gi0 = min(max((int)floorf(gx0), 0), NWW-1);
    gj0 = min(max((int)floorf(gy0), 0), NHH-1);
#pragma unroll
    for (int k = 0; k < KK; ++k){
      txv[k] = trow[1+2*k]*(float)NWW - (float)gi0;
      tyv[k] = trow[2+2*k]*(float)NHH - (float)gj0;
    }
    // best anchor by IoU (first max wins)
    float gw = trow[LL-2]*(float)NWW, gh = trow[LL-1]*(float)NHH;
    float best = -1.0f;
    for (int a = 0; a < NANC; ++a){
      float aw = c_anch[2*a], ah = c_anch[2*a+1];
      float inter = fminf(aw, gw) * fminf(ah, gh);
      float iou = inter / (aw*ah + gw*gh - inter);
      if (iou > best){ best = iou; bn = a; }
    }
    key = bn*NPIX + gj0*NWW + gi0;
    keys[t] = key;

    // conf_t from pred_box at the wrapped flat index (reference's mod arithmetic)
    long f = (long)b*NANCHT - NPIX + gj0*NWW + gi0;
    if (f < 0) f += NCELLT;
    int bb  = (int)(f / NANCHT);
    int rr  = (int)(f - (long)bb*NANCHT);
    int aa  = rr / NPIX;
    int rr2 = rr - aa*NPIX;
    int jj  = rr2 / NWW;
    int ii  = rr2 - jj*NWW;
    const float* pbase = outp + (((size_t)bb*NANC + aa)*CHC)*NPIX + rr2;
    float s = 0.0f;
#pragma unroll
    for (int k = 0; k < KK; ++k){
      float rx = pbase[(2*k)*NPIX], ry = pbase[(2*k+1)*NPIX];
      if (k == 0){ rx = sigmoidf_(rx); ry = sigmoidf_(ry); }
      float Pxx = (rx + (float)ii)*SXW, Pyy = (ry + (float)jj)*SYH;
      float dx = Pxx - trow[1+2*k]*640.0f;
      float dy = Pyy - trow[2+2*k]*480.0f;
      float d  = fast_sqrt(fmaf(dy, dy, dx*dx));
      float e  = fast_exp2(fmaf(d, -K2C, K1C));
      s += fmaxf(e, 1.0f);
    }
    conf_t = (s - 9.0f) * CONF_T_SCALE;
  }
  __syncthreads();

  // winner = last valid t writing this (bn,gj,gi) cell (scan overwrite semantics)
  bool winner = valid;
  if (valid){
    for (int u = t+1; u < nv; ++u) if (keys[u] == key){ winner = false; break; }
  }

  double lx = 0.0, ly = 0.0, lcls = 0.0, lcf = 0.0;
  if (winner){
    const float* cbase = outp + (((size_t)b*NANC + bn)*CHC)*NPIX + gj0*NWW + gi0;
    float sx = 0.0f, sy = 0.0f;
#pragma unroll
    for (int k = 0; k < KK; ++k){
      float rx = cbase[(2*k)*NPIX], ry = cbase[(2*k+1)*NPIX];
      if (k == 0){ rx = sigmoidf_(rx); ry = sigmoidf_(ry); }
      float dx = rx - txv[k], dy = ry - tyv[k];
      sx = fmaf(dx, dx, sx); sy = fmaf(dy, dy, sy);
    }
    lx = 0.5*(double)sx; ly = 0.5*(double)sy;

    // class CE (log_softmax over 13 logits)
    float lg[NCLS], mx = -1e30f;
#pragma unroll
    for (int c = 0; c < NCLS; ++c){ lg[c] = cbase[(2*KK+1+c)*NPIX]; mx = fmaxf(mx, lg[c]); }
    float se = 0.0f;
#pragma unroll
    for (int c = 0; c < NCLS; ++c) se += fast_exp2((lg[c]-mx)*LOG2E_F);
    int label = min(max((int)tcls, 0), NCLS-1);
    lcls = (double)(mx + logf(se) - lg[label]);

    // conf-loss correction at object cell: + 0.5*OBJ*(conf-conf_t)^2 - base term
    float cf = sigmoidf_(cbase[(2*KK)*NPIX]);
    int idx = bn*NPIX + gj0*NWW + gi0;
    int m0 = (maskw[(size_t)b*MWPB + (idx >> 5)] >> (idx & 31)) & 1;
    float dcf = cf - conf_t;
    lcf = 0.5*OBJ_W*(double)(dcf*dcf) - (m0 ? 0.5*(double)(cf*cf) : 0.0);
  }

  // single-wave block: shfl reduce doubles, write per-batch partials
#pragma unroll
  for (int o = 32; o > 0; o >>= 1){
    lx  += __shfl_xor(lx,  o, 64);
    ly  += __shfl_xor(ly,  o, 64);
    lcls+= __shfl_xor(lcls,o, 64);
    lcf += __shfl_xor(lcf, o, 64);
  }
  if (threadIdx.x == 0){
    double* bp = bc_part + (size_t)b*4;
    bp[0] = lx; bp[1] = ly; bp[2] = lcls; bp[3] = lcf;
  }
}

// ---------------- finalize: deterministic reduce + epoch gate ----------------
__global__ __launch_bounds__(256) void finalize_kernel(
    const double* __restrict__ bc_part, const double* __restrict__ partials,
    const int* __restrict__ epoch_p, float* __restrict__ outv){
  int tid = threadIdx.x;
  double vx=0, vy=0, vc=0, vf=0, vb=0;
  for (int i = tid; i < NBB; i += 256){
    vx += bc_part[4*i]; vy += bc_part[4*i+1];
    vc += bc_part[4*i+2]; vf += bc_part[4*i+3];
  }
  for (int i = tid; i < 14*NBB; i += 256) vb += partials[i];
#pragma unroll
  for (int o = 32; o > 0; o >>= 1){
    vx += __shfl_xor(vx, o, 64); vy += __shfl_xor(vy, o, 64);
    vc += __shfl_xor(vc, o, 64); vf += __shfl_xor(vf, o, 64);
    vb += __shfl_xor(vb, o, 64);
  }
  __shared__ double sm[5][4];
  int wid = tid >> 6, lane = tid & 63;
  if (lane == 0){ sm[0][wid]=vx; sm[1][wid]=vy; sm[2][wid]=vc; sm[3][wid]=vf; sm[4][wid]=vb; }
  __syncthreads();
  if (tid == 0){
    double fx=0, fy=0, fc=0, ff=0, fb=0;
    for (int w = 0; w < 4; ++w){ fx+=sm[0][w]; fy+=sm[1][w]; fc+=sm[2][w]; ff+=sm[3][w]; fb+=sm[4][w]; }
    double loss = fx + fy + fc;
    if (*epoch_p > EPOCH_PRETRAIN) loss += ff + fb;
    outv[0] = (float)loss;
  }
}

extern "C" void kernel_launch(void* const* d_in, const int* in_sizes, int n_in,
                              void* d_out, int out_size, void* d_ws, size_t ws_size,
                              hipStream_t stream){
  (void)in_sizes; (void)n_in; (void)out_size; (void)ws_size;
  const float* outp = (const float*)d_in[0];
  const float* tgt  = (const float*)d_in[1];
  const int*   ep   = (const int*)d_in[2];
  float* outv = (float*)d_out;
  char* ws = (char*)d_ws;

  double* bc_part  = (double*)(ws);                  // 4096 B
  double* partials = (double*)(ws + 4096);           // 14336 B
  float*  gts_neg  = (float*) (ws + 18432);          // 512000 B
  int*    nvalid   = (int*)   (ws + 530432);         // 512 B
  unsigned int* maskw = (unsigned int*)(ws + 530944); // 54272 B

  prep_kernel<<<dim3(NBB), dim3(64), 0, stream>>>(tgt, gts_neg, nvalid);
  region_confmask_kernel<<<dim3(14, NBB), dim3(256), 0, stream>>>(outp, gts_neg, nvalid, maskw, partials);
  scatter_loss_kernel<<<dim3(NBB), dim3(64), 0, stream>>>(outp, tgt, nvalid, maskw, bc_part);
  finalize_kernel<<<dim3(1), dim3(256), 0, stream>>>(bc_part, partials, ep, outv);
}